// Round 4
// baseline (227.142 us; speedup 1.0000x reference)
//
#include <hip/hip_runtime.h>
#include <hip/hip_bf16.h>
#include <math.h>

// IntegralTransform via bf16 MFMA (16x16x32). Persistent grid: 1024 blocks x
// 4 waves; each wave loops over ~12 points (one point = 32 edges = 2 M=16
// tiles, processed INTERLEAVED for ILP). Weight B-fragments loaded once per
// wave (live in AGPRs). h1/h2 round-trip per-wave LDS bufB with a COLUMN
// PERMUTATION (phys col = 4*c16+nb) so each lane stores its 4 accs with one
// ds_write_b64; W2/W3 rows are permuted at load time to compensate.
// wts rides in bufA col 38 (bf16) and is multiplied by zeroed W1 rows.
// No __syncthreads: buffers are per-wave; same-wave DS ops are in order.

typedef __attribute__((ext_vector_type(8))) short short8;
typedef __attribute__((ext_vector_type(4))) float floatx4;

__device__ __forceinline__ unsigned short bf16rne(float f) {
    unsigned int u = __float_as_uint(f);
    u += 0x7fffu + ((u >> 16) & 1u);
    return (unsigned short)(u >> 16);
}
__device__ __forceinline__ unsigned int pk2(float a, float b) {
    union { __hip_bfloat162 h; unsigned int u; } cv;
    cv.h = __float22bfloat162_rn(make_float2(a, b));
    return cv.u;
}
__device__ __forceinline__ float bf16f(unsigned short u) {
    return __uint_as_float(((unsigned int)u) << 16);
}
// sigmoid-form gelu: x * sigmoid(1.702x) = x/(1+exp(-1.702x)).
// |err vs exact-erf gelu| <= ~0.02; threshold 3.1e-1. 5 VALU ops, 2 trans.
__device__ __forceinline__ float gelu_fast(float x) {
    float e = __expf(-1.702f * x);
    return x * __builtin_amdgcn_rcpf(1.0f + e);
}

#define MFMA16(a, b, c) __builtin_amdgcn_mfma_f32_16x16x32_bf16(a, b, c, 0, 0, 0)

__global__ __launch_bounds__(256, 4) void it_mfma(
    const float* __restrict__ y, const float* __restrict__ fy,
    const float* __restrict__ wts,
    const float* __restrict__ W1, const float* __restrict__ b1,
    const float* __restrict__ W2, const float* __restrict__ b2,
    const float* __restrict__ W3, const float* __restrict__ b3,
    const int* __restrict__ nbr,
    float* __restrict__ out, int npts)
{
    __shared__ unsigned short lds[4][2][32][72];   // 36864 B

    const int lane = threadIdx.x & 63;
    const int wv   = threadIdx.x >> 6;
    const int quad = lane >> 4;
    const int c16  = lane & 15;
    const int wgid   = blockIdx.x * 4 + wv;
    const int nwaves = gridDim.x * 4;

    // ---- weight fragments (bf16, B-layout: k = 32*kb + 8*quad + j, n = 16*nb + c16)
    // W1 k-permutation: k'<32 -> row 6+k' (fy block); 32..37 -> rows 0..5; else 0.
    // W2/W3 row index un-permutes the h storage: logical(p) = (p&3)*16 + (p>>2).
    short8 w1f[2][4], w2f[2][4], w3f[2][2];
    #pragma unroll
    for (int kb = 0; kb < 2; ++kb)
        #pragma unroll
        for (int nb = 0; nb < 4; ++nb)
            #pragma unroll
            for (int j = 0; j < 8; ++j) {
                int kp = kb * 32 + quad * 8 + j;
                int n  = nb * 16 + c16;
                int r  = (kp < 32) ? (6 + kp) : (kp < 38 ? kp - 32 : -1);
                float v = (r >= 0) ? W1[r * 64 + n] : 0.f;
                w1f[kb][nb][j] = (short)bf16rne(v);
            }
    #pragma unroll
    for (int kb = 0; kb < 2; ++kb)
        #pragma unroll
        for (int nb = 0; nb < 4; ++nb)
            #pragma unroll
            for (int j = 0; j < 8; ++j) {
                int kp = kb * 32 + quad * 8 + j;
                int kl = (kp & 3) * 16 + (kp >> 2);      // logical h1 index
                w2f[kb][nb][j] = (short)bf16rne(W2[kl * 64 + nb * 16 + c16]);
            }
    #pragma unroll
    for (int kb = 0; kb < 2; ++kb)
        #pragma unroll
        for (int nb = 0; nb < 2; ++nb)
            #pragma unroll
            for (int j = 0; j < 8; ++j) {
                int kp = kb * 32 + quad * 8 + j;
                int kl = (kp & 3) * 16 + (kp >> 2);      // logical h2 index
                w3f[kb][nb][j] = (short)bf16rne(W3[kl * 32 + nb * 16 + c16]);
            }
    float b1v[4], b2v[4], b3v0, b3v1;
    #pragma unroll
    for (int nb = 0; nb < 4; ++nb) { b1v[nb] = b1[nb * 16 + c16]; b2v[nb] = b2[nb * 16 + c16]; }
    b3v0 = b3[c16]; b3v1 = b3[16 + c16];

    unsigned short (*bufA)[72] = lds[wv][0];
    unsigned short (*bufB)[72] = lds[wv][1];

    // one-time zero of bufA cols 40..63 (stage rewrites only cols 0..39)
    if (lane < 32) {
        uint4 z = make_uint4(0u, 0u, 0u, 0u);
        *(uint4*)&bufA[lane][40] = z;
        *(uint4*)&bufA[lane][48] = z;
        *(uint4*)&bufA[lane][56] = z;
    }

    const floatx4 fz = {0.f, 0.f, 0.f, 0.f};

    // prefetch first point's neighbor row
    int j_next = 0;
    if (wgid < npts) j_next = nbr[wgid * 32 + (lane & 31)];

    for (int p = wgid; p < npts; p += nwaves) {
        const int pu  = __builtin_amdgcn_readfirstlane(p);
        const int j32 = j_next;
        // ---- stage: 2 lanes per edge-row pack fy halves; lanes<32 pack y+w ----
        const int row  = lane >> 1;
        const int jr   = __shfl(j32, row, 64);
        const int half = (lane & 1) << 4;              // cols 0..15 or 16..31
        const float4* fp = (const float4*)(fy + (long)jr * 32 + half);
        float4 v0 = fp[0], v1 = fp[1], v2 = fp[2], v3 = fp[3];
        float yj0 = 0.f, yj1 = 0.f, yj2 = 0.f, yi0 = 0.f, yi1 = 0.f, yi2 = 0.f, wj = 0.f;
        if (lane < 32) {
            yj0 = y[3 * j32]; yj1 = y[3 * j32 + 1]; yj2 = y[3 * j32 + 2];
            yi0 = y[3 * pu];  yi1 = y[3 * pu + 1];  yi2 = y[3 * pu + 2];
            wj  = wts[j32];
        }
        // prefetch next point's neighbor row (hidden behind this point's compute)
        {
            int pn = p + nwaves;
            if (pn < npts) j_next = nbr[pn * 32 + (lane & 31)];
        }
        *(uint4*)&bufA[row][half] =
            make_uint4(pk2(v0.x, v0.y), pk2(v0.z, v0.w), pk2(v1.x, v1.y), pk2(v1.z, v1.w));
        *(uint4*)&bufA[row][half + 8] =
            make_uint4(pk2(v2.x, v2.y), pk2(v2.z, v2.w), pk2(v3.x, v3.y), pk2(v3.z, v3.w));
        if (lane < 32) {
            *(uint4*)&bufA[lane][32] =
                make_uint4(pk2(yj0, yj1), pk2(yj2, yi0), pk2(yi1, yi2), pk2(wj, 0.f));
        }

        // ---- layer 1 (both tiles interleaved) ----
        short8 a0[2], a1[2];
        #pragma unroll
        for (int t = 0; t < 2; ++t) {
            const int arow = t * 16 + c16;
            a0[t] = *(const short8*)&bufA[arow][quad * 8];
            a1[t] = *(const short8*)&bufA[arow][32 + quad * 8];
        }
        floatx4 acc[2][4];
        #pragma unroll
        for (int t = 0; t < 2; ++t)
            #pragma unroll
            for (int nb = 0; nb < 4; ++nb) {
                acc[t][nb] = MFMA16(a0[t], w1f[0][nb], fz);
                acc[t][nb] = MFMA16(a1[t], w1f[1][nb], acc[t][nb]);
            }
        #pragma unroll
        for (int t = 0; t < 2; ++t)
            #pragma unroll
            for (int r = 0; r < 4; ++r) {
                float g0 = gelu_fast(acc[t][0][r] + b1v[0]);
                float g1 = gelu_fast(acc[t][1][r] + b1v[1]);
                float g2 = gelu_fast(acc[t][2][r] + b1v[2]);
                float g3 = gelu_fast(acc[t][3][r] + b1v[3]);
                *(uint2*)&bufB[t * 16 + quad * 4 + r][4 * c16] =
                    make_uint2(pk2(g0, g1), pk2(g2, g3));
            }

        // ---- layer 2 ----
        short8 h0[2], h1[2];
        #pragma unroll
        for (int t = 0; t < 2; ++t) {
            const int arow = t * 16 + c16;
            h0[t] = *(const short8*)&bufB[arow][quad * 8];
            h1[t] = *(const short8*)&bufB[arow][32 + quad * 8];
        }
        #pragma unroll
        for (int t = 0; t < 2; ++t)
            #pragma unroll
            for (int nb = 0; nb < 4; ++nb) {
                acc[t][nb] = MFMA16(h0[t], w2f[0][nb], fz);
                acc[t][nb] = MFMA16(h1[t], w2f[1][nb], acc[t][nb]);
            }
        #pragma unroll
        for (int t = 0; t < 2; ++t)
            #pragma unroll
            for (int r = 0; r < 4; ++r) {
                float g0 = gelu_fast(acc[t][0][r] + b2v[0]);
                float g1 = gelu_fast(acc[t][1][r] + b2v[1]);
                float g2 = gelu_fast(acc[t][2][r] + b2v[2]);
                float g3 = gelu_fast(acc[t][3][r] + b2v[3]);
                *(uint2*)&bufB[t * 16 + quad * 4 + r][4 * c16] =
                    make_uint2(pk2(g0, g1), pk2(g2, g3));
            }

        // ---- layer 3 ----
        short8 g0f[2], g1f[2];
        #pragma unroll
        for (int t = 0; t < 2; ++t) {
            const int arow = t * 16 + c16;
            g0f[t] = *(const short8*)&bufB[arow][quad * 8];
            g1f[t] = *(const short8*)&bufB[arow][32 + quad * 8];
        }
        floatx4 o[2][2];
        #pragma unroll
        for (int t = 0; t < 2; ++t)
            #pragma unroll
            for (int nb = 0; nb < 2; ++nb) {
                o[t][nb] = MFMA16(g0f[t], w3f[0][nb], fz);
                o[t][nb] = MFMA16(g1f[t], w3f[1][nb], o[t][nb]);
            }

        // ---- epilogue: (o + b3) * fy[j] * w[j] (all from bufA), row-accumulate ----
        float colsum0 = 0.f, colsum1 = 0.f;
        #pragma unroll
        for (int t = 0; t < 2; ++t)
            #pragma unroll
            for (int r = 0; r < 4; ++r) {
                const int orow = t * 16 + quad * 4 + r;
                float wr = bf16f(bufA[orow][38]);
                float f0 = bf16f(bufA[orow][c16]);
                float f1 = bf16f(bufA[orow][16 + c16]);
                colsum0 = fmaf((o[t][0][r] + b3v0) * f0, wr, colsum0);
                colsum1 = fmaf((o[t][1][r] + b3v1) * f1, wr, colsum1);
            }

        colsum0 += __shfl_xor(colsum0, 16, 64);
        colsum0 += __shfl_xor(colsum0, 32, 64);
        colsum1 += __shfl_xor(colsum1, 16, 64);
        colsum1 += __shfl_xor(colsum1, 32, 64);
        if (lane < 32)
            out[pu * 32 + lane] = (lane < 16) ? colsum0 : colsum1;
    }
}

extern "C" void kernel_launch(void* const* d_in, const int* in_sizes, int n_in,
                              void* d_out, int out_size, void* d_ws, size_t ws_size,
                              hipStream_t stream) {
    const float* y  = (const float*)d_in[0];
    const float* fy = (const float*)d_in[1];
    const float* wt = (const float*)d_in[2];
    const float* W1 = (const float*)d_in[3];
    const float* b1 = (const float*)d_in[4];
    const float* W2 = (const float*)d_in[5];
    const float* b2 = (const float*)d_in[6];
    const float* W3 = (const float*)d_in[7];
    const float* b3 = (const float*)d_in[8];
    const int* nbr  = (const int*)d_in[9];
    const int E = in_sizes[9];
    const int npts = E >> 5;              // K = 32 fixed
    float* out = (float*)d_out;

    // persistent: 1024 blocks x 4 waves = 4096 waves, fully resident
    hipLaunchKernelGGL(it_mfma, dim3(1024), dim3(256), 0, stream,
                       y, fy, wt, W1, b1, W2, b2, W3, b3, nbr, out, npts);
}